// Round 7
// baseline (305.533 us; speedup 1.0000x reference)
//
#include <hip/hip_runtime.h>
#include <hip/hip_bf16.h>
#include <math.h>

#define N_NODES 10000
#define D 128
#define NCOPY 8
#define APAD 132

typedef unsigned int uint_t;
typedef unsigned short ushort_t;

// float -> bf16 bits, round-nearest-even (finite inputs only)
__device__ inline uint_t f2bf_bits(float f) {
    uint_t u = __float_as_uint(f);
    return (u + 0x7fffu + ((u >> 16) & 1u)) >> 16;
}
__device__ inline uint_t pack_bf2(float lo, float hi) {
    return (f2bf_bits(hi) << 16) | f2bf_bits(lo);
}
__device__ inline void acc_bf8(uint4 v, float4& aA, float4& aB) {
    aA.x += __uint_as_float(v.x << 16);
    aA.y += __uint_as_float(v.x & 0xffff0000u);
    aA.z += __uint_as_float(v.y << 16);
    aA.w += __uint_as_float(v.y & 0xffff0000u);
    aB.x += __uint_as_float(v.z << 16);
    aB.y += __uint_as_float(v.z & 0xffff0000u);
    aB.z += __uint_as_float(v.w << 16);
    aB.w += __uint_as_float(v.w & 0xffff0000u);
}

// ---------------- tiny zero fill ----------------
__global__ void zero_kernel(uint4* __restrict__ p, int n16) {
    int i = blockIdx.x * blockDim.x + threadIdx.x;
    if (i < n16) p[i] = make_uint4(0u, 0u, 0u, 0u);
}

// ---------------- CSR build ----------------
__global__ void rank_kernel(const int* __restrict__ dst, int E,
                            int* __restrict__ deg8, int* __restrict__ pos) {
    int i = blockIdx.x * blockDim.x + threadIdx.x;
    if (i < E) {
        int c = blockIdx.x & (NCOPY - 1);
        pos[i] = atomicAdd(&deg8[c * N_NODES + dst[i]], 1);
    }
}

__global__ void sumdeg_kernel(const int* __restrict__ deg8, int* __restrict__ tot, int n) {
    int i = blockIdx.x * blockDim.x + threadIdx.x;
    if (i < n) {
        int s = 0;
#pragma unroll
        for (int c = 0; c < NCOPY; ++c) s += deg8[c * N_NODES + i];
        tot[i] = s;
    }
}

#define SCAN_PER 10
__global__ __launch_bounds__(1024) void scan_kernel(const int* __restrict__ tot,
                                                    int* __restrict__ offsets, int n) {
    __shared__ int wsum[16];
    __shared__ int wpre[16];
    int tid = threadIdx.x;
    int lane = tid & 63, wid = tid >> 6;
    int base = tid * SCAN_PER;
    int loc[SCAN_PER];
    int s = 0;
#pragma unroll
    for (int q = 0; q < SCAN_PER; ++q) {
        int idx = base + q;
        int v = (idx < n) ? tot[idx] : 0;
        s += v;
        loc[q] = s;
    }
    int mysum = s;
#pragma unroll
    for (int off = 1; off < 64; off <<= 1) {
        int t = __shfl_up(s, off, 64);
        if (lane >= off) s += t;
    }
    if (lane == 63) wsum[wid] = s;
    __syncthreads();
    if (wid == 0 && lane < 16) {
        int v = wsum[lane];
        int ss = v;
#pragma unroll
        for (int off = 1; off < 16; off <<= 1) {
            int t = __shfl_up(ss, off, 16);
            if ((lane & 15) >= off) ss += t;
        }
        wpre[lane] = ss - v;
    }
    __syncthreads();
    int thread_excl = wpre[wid] + (s - mysum);
#pragma unroll
    for (int q = 0; q < SCAN_PER; ++q) {
        int idx = base + q;
        if (idx < n) offsets[idx + 1] = thread_excl + loc[q];
    }
    if (tid == 0) offsets[0] = 0;
}

__global__ void base8_kernel(const int* __restrict__ deg8, const int* __restrict__ offsets,
                             int* __restrict__ base8, int n) {
    int i = blockIdx.x * blockDim.x + threadIdx.x;
    if (i < n) {
        int run = offsets[i];
#pragma unroll
        for (int c = 0; c < NCOPY; ++c) {
            base8[c * N_NODES + i] = run;
            run += deg8[c * N_NODES + i];
        }
    }
}

__global__ void csr_write_kernel(const int* __restrict__ src, const int* __restrict__ dst,
                                 const int* __restrict__ pos, int E,
                                 const int* __restrict__ base8, int* __restrict__ csr_src) {
    int i = blockIdx.x * blockDim.x + threadIdx.x;
    if (i < E) {
        int c = (i >> 8) & (NCOPY - 1);  // matches rank_kernel (256 thr/block)
        csr_src[base8[c * N_NODES + dst[i]] + pos[i]] = src[i];
    }
}

// ---------------- fp32 -> bf16 mirror ----------------
__global__ void f2bf_kernel(const float* __restrict__ in, ushort_t* __restrict__ out, int n8) {
    int i = blockIdx.x * blockDim.x + threadIdx.x;
    if (i >= n8) return;
    const float4* p = (const float4*)in + (size_t)i * 2;
    float4 a = p[0], b = p[1];
    uint4 o;
    o.x = pack_bf2(a.x, a.y);
    o.y = pack_bf2(a.z, a.w);
    o.z = pack_bf2(b.x, b.y);
    o.w = pack_bf2(b.z, b.w);
    ((uint4*)out)[i] = o;
}

// ---------------- fused SAGE layer ----------------
// Per block: 32 output rows. Phase A: gather-mean of h16 neighbors -> As1 (LDS),
// stage fp32 self rows -> As2. Phase B: out = relu(As1@W1 + As2@W2 + b).
// If Wc != null: instead of writing out, compute sigmoid(out_row . Wc + bc) -> cls.
__global__ __launch_bounds__(256) void sage_fused_kernel(
        const ushort_t* __restrict__ h16, const float* __restrict__ A2,
        const int* __restrict__ offsets, const int* __restrict__ csr_src,
        const float* __restrict__ W1, const float* __restrict__ W2,
        const float* __restrict__ bias,
        float* __restrict__ out, ushort_t* __restrict__ out16,
        const float* __restrict__ Wc, const float* __restrict__ bcls,
        float* __restrict__ cls, int M) {
    __shared__ float As1[32][APAD];
    __shared__ float As2[32][APAD];
    __shared__ float Ws1[32][D];
    __shared__ float Ws2[32][D];
    int tid = threadIdx.x;
    int r0g = blockIdx.x * 32;

    // ---- stage fp32 self rows ----
    {
        int row = tid >> 3;
        int rg = r0g + row;
        bool ok = rg < M;
#pragma unroll
        for (int q = 0; q < 4; ++q) {
            int col = ((tid & 7) + q * 8) * 4;
            float4 a2 = make_float4(0.f, 0.f, 0.f, 0.f);
            if (ok) a2 = *(const float4*)&A2[rg * D + col];
            *(float4*)&As2[row][col] = a2;
        }
    }
    // ---- aggregate neighbors (bf16 gather) -> As1 ----
    {
        int wv = tid >> 6;       // wave 0..3
        int lane = tid & 63;
        int g = lane >> 4;       // edge group 0..3
        int fl = lane & 15;      // feature block (8 bf16 = 16B)
        for (int i = 0; i < 8; ++i) {
            int r = wv * 8 + i;
            int node = r0g + r;
            int beg = 0, end = 0;
            if (node < M) { beg = offsets[node]; end = offsets[node + 1]; }
            float4 aA = make_float4(0.f, 0.f, 0.f, 0.f);
            float4 aB = make_float4(0.f, 0.f, 0.f, 0.f);
            for (int e = beg + g; e < end; e += 4) {
                int s = csr_src[e];
                uint4 v = *(const uint4*)&h16[s * D + fl * 8];
                acc_bf8(v, aA, aB);
            }
            // reduce across the 4 edge groups (lane bits 4,5)
            aA.x += __shfl_xor(aA.x, 16, 64); aA.y += __shfl_xor(aA.y, 16, 64);
            aA.z += __shfl_xor(aA.z, 16, 64); aA.w += __shfl_xor(aA.w, 16, 64);
            aB.x += __shfl_xor(aB.x, 16, 64); aB.y += __shfl_xor(aB.y, 16, 64);
            aB.z += __shfl_xor(aB.z, 16, 64); aB.w += __shfl_xor(aB.w, 16, 64);
            aA.x += __shfl_xor(aA.x, 32, 64); aA.y += __shfl_xor(aA.y, 32, 64);
            aA.z += __shfl_xor(aA.z, 32, 64); aA.w += __shfl_xor(aA.w, 32, 64);
            aB.x += __shfl_xor(aB.x, 32, 64); aB.y += __shfl_xor(aB.y, 32, 64);
            aB.z += __shfl_xor(aB.z, 32, 64); aB.w += __shfl_xor(aB.w, 32, 64);
            if (lane < 16) {
                int cnt = end - beg;
                float inv = (cnt > 0) ? (1.0f / (float)cnt) : 0.f;
                aA.x *= inv; aA.y *= inv; aA.z *= inv; aA.w *= inv;
                aB.x *= inv; aB.y *= inv; aB.z *= inv; aB.w *= inv;
                *(float4*)&As1[r][fl * 8] = aA;
                *(float4*)&As1[r][fl * 8 + 4] = aB;
            }
        }
    }

    int ty = tid >> 4;
    int tx = tid & 15;
    int c0 = tx * 8;
    int rl0 = ty, rl1 = ty + 16;

    float4 b_lo = *(const float4*)&bias[c0];
    float4 b_hi = *(const float4*)&bias[c0 + 4];

    float4 acc0l = make_float4(0.f, 0.f, 0.f, 0.f);
    float4 acc0h = make_float4(0.f, 0.f, 0.f, 0.f);
    float4 acc1l = make_float4(0.f, 0.f, 0.f, 0.f);
    float4 acc1h = make_float4(0.f, 0.f, 0.f, 0.f);

    for (int kc = 0; kc < 4; ++kc) {
        __syncthreads();   // kc=0: also covers As1/As2 staging
        {
            int wrow = tid >> 3;
            int grow = kc * 32 + wrow;
#pragma unroll
            for (int q = 0; q < 4; ++q) {
                int col = ((tid & 7) + q * 8) * 4;
                float4 w1 = *(const float4*)&W1[grow * D + col];
                float4 w2 = *(const float4*)&W2[grow * D + col];
                *(float4*)&Ws1[wrow][col] = w1;
                *(float4*)&Ws2[wrow][col] = w2;
            }
        }
        __syncthreads();

#pragma unroll 4
        for (int kk = 0; kk < 32; ++kk) {
            int k = kc * 32 + kk;
            float a10 = As1[rl0][k];
            float a11 = As1[rl1][k];
            float a20 = As2[rl0][k];
            float a21 = As2[rl1][k];
            float4 w1l = *(const float4*)&Ws1[kk][c0];
            float4 w1h = *(const float4*)&Ws1[kk][c0 + 4];
            float4 w2l = *(const float4*)&Ws2[kk][c0];
            float4 w2h = *(const float4*)&Ws2[kk][c0 + 4];
            acc0l.x += a10 * w1l.x + a20 * w2l.x;
            acc0l.y += a10 * w1l.y + a20 * w2l.y;
            acc0l.z += a10 * w1l.z + a20 * w2l.z;
            acc0l.w += a10 * w1l.w + a20 * w2l.w;
            acc0h.x += a10 * w1h.x + a20 * w2h.x;
            acc0h.y += a10 * w1h.y + a20 * w2h.y;
            acc0h.z += a10 * w1h.z + a20 * w2h.z;
            acc0h.w += a10 * w1h.w + a20 * w2h.w;
            acc1l.x += a11 * w1l.x + a21 * w2l.x;
            acc1l.y += a11 * w1l.y + a21 * w2l.y;
            acc1l.z += a11 * w1l.z + a21 * w2l.z;
            acc1l.w += a11 * w1l.w + a21 * w2l.w;
            acc1h.x += a11 * w1h.x + a21 * w2h.x;
            acc1h.y += a11 * w1h.y + a21 * w2h.y;
            acc1h.z += a11 * w1h.z + a21 * w2h.z;
            acc1h.w += a11 * w1h.w + a21 * w2h.w;
        }
    }

    int rg0 = r0g + rl0;
    int rg1 = r0g + rl1;
    float4 vl0, vh0, vl1, vh1;
    vl0.x = fmaxf(acc0l.x + b_lo.x, 0.f); vl0.y = fmaxf(acc0l.y + b_lo.y, 0.f);
    vl0.z = fmaxf(acc0l.z + b_lo.z, 0.f); vl0.w = fmaxf(acc0l.w + b_lo.w, 0.f);
    vh0.x = fmaxf(acc0h.x + b_hi.x, 0.f); vh0.y = fmaxf(acc0h.y + b_hi.y, 0.f);
    vh0.z = fmaxf(acc0h.z + b_hi.z, 0.f); vh0.w = fmaxf(acc0h.w + b_hi.w, 0.f);
    vl1.x = fmaxf(acc1l.x + b_lo.x, 0.f); vl1.y = fmaxf(acc1l.y + b_lo.y, 0.f);
    vl1.z = fmaxf(acc1l.z + b_lo.z, 0.f); vl1.w = fmaxf(acc1l.w + b_lo.w, 0.f);
    vh1.x = fmaxf(acc1h.x + b_hi.x, 0.f); vh1.y = fmaxf(acc1h.y + b_hi.y, 0.f);
    vh1.z = fmaxf(acc1h.z + b_hi.z, 0.f); vh1.w = fmaxf(acc1h.w + b_hi.w, 0.f);

    if (Wc) {
        // classifier fused: p = relu_row . Wc, reduce over 16 col-threads, sigmoid
        float4 wl = *(const float4*)&Wc[c0];
        float4 wh = *(const float4*)&Wc[c0 + 4];
        float p0 = vl0.x * wl.x + vl0.y * wl.y + vl0.z * wl.z + vl0.w * wl.w
                 + vh0.x * wh.x + vh0.y * wh.y + vh0.z * wh.z + vh0.w * wh.w;
        float p1 = vl1.x * wl.x + vl1.y * wl.y + vl1.z * wl.z + vl1.w * wl.w
                 + vh1.x * wh.x + vh1.y * wh.y + vh1.z * wh.z + vh1.w * wh.w;
#pragma unroll
        for (int off = 1; off <= 8; off <<= 1) {
            p0 += __shfl_xor(p0, off, 64);
            p1 += __shfl_xor(p1, off, 64);
        }
        if (tx == 0) {
            float b = bcls[0];
            if (rg0 < M) cls[rg0] = 1.0f / (1.0f + expf(-(p0 + b)));
            if (rg1 < M) cls[rg1] = 1.0f / (1.0f + expf(-(p1 + b)));
        }
    } else {
        if (rg0 < M) {
            *(float4*)&out[rg0 * D + c0] = vl0;
            *(float4*)&out[rg0 * D + c0 + 4] = vh0;
            if (out16) {
                uint4 o;
                o.x = pack_bf2(vl0.x, vl0.y); o.y = pack_bf2(vl0.z, vl0.w);
                o.z = pack_bf2(vh0.x, vh0.y); o.w = pack_bf2(vh0.z, vh0.w);
                *(uint4*)&out16[rg0 * D + c0] = o;
            }
        }
        if (rg1 < M) {
            *(float4*)&out[rg1 * D + c0] = vl1;
            *(float4*)&out[rg1 * D + c0 + 4] = vh1;
            if (out16) {
                uint4 o;
                o.x = pack_bf2(vl1.x, vl1.y); o.y = pack_bf2(vl1.z, vl1.w);
                o.z = pack_bf2(vh1.x, vh1.y); o.w = pack_bf2(vh1.z, vh1.w);
                *(uint4*)&out16[rg1 * D + c0] = o;
            }
        }
    }
}

extern "C" void kernel_launch(void* const* d_in, const int* in_sizes, int n_in,
                              void* d_out, int out_size, void* d_ws, size_t ws_size,
                              hipStream_t stream) {
    const float* x   = (const float*)d_in[0];
    const int* eidx  = (const int*)d_in[1];
    int E = in_sizes[1] / 2;
    const int* src = eidx;
    const int* dst = eidx + E;
    const float* W1l = (const float*)d_in[2];
    const float* b1  = (const float*)d_in[3];
    const float* W1r = (const float*)d_in[4];
    const float* W2l = (const float*)d_in[5];
    const float* b2  = (const float*)d_in[6];
    const float* W2r = (const float*)d_in[7];
    const float* W3l = (const float*)d_in[8];
    const float* b3  = (const float*)d_in[9];
    const float* W3r = (const float*)d_in[10];
    const float* Wc  = (const float*)d_in[11];
    const float* bc  = (const float*)d_in[12];
    float* out = (float*)d_out;

    // workspace carve-up
    char* p = (char*)d_ws;
    int* deg8      = (int*)p;  p += (size_t)NCOPY * N_NODES * 4;
    int* base8     = (int*)p;  p += (size_t)NCOPY * N_NODES * 4;
    int* offsets   = (int*)p;  p += 40960;
    int* tot       = (int*)p;  p += 40960;
    int* csr_src   = (int*)p;  p += (size_t)E * 4;
    int* pos       = (int*)p;  p += (size_t)E * 4;
    float* hA      = (float*)p; p += (size_t)N_NODES * D * 4;
    float* hB      = (float*)p; p += (size_t)N_NODES * D * 4;
    ushort_t* h16a = (ushort_t*)p; p += (size_t)N_NODES * D * 2;
    ushort_t* h16b = (ushort_t*)p; p += (size_t)N_NODES * D * 2;

    // zero deg8
    int zn16 = (NCOPY * N_NODES * 4) / 16;
    zero_kernel<<<(zn16 + 255) / 256, 256, 0, stream>>>((uint4*)deg8, zn16);

    // bf16 mirror of x
    int n8 = N_NODES * D / 8;
    f2bf_kernel<<<(n8 + 255) / 256, 256, 0, stream>>>(x, h16a, n8);

    int eb = (E + 255) / 256;
    int nb = (N_NODES + 255) / 256;
    rank_kernel<<<eb, 256, 0, stream>>>(dst, E, deg8, pos);
    sumdeg_kernel<<<nb, 256, 0, stream>>>(deg8, tot, N_NODES);
    scan_kernel<<<1, 1024, 0, stream>>>(tot, offsets, N_NODES);
    base8_kernel<<<nb, 256, 0, stream>>>(deg8, offsets, base8, N_NODES);
    csr_write_kernel<<<eb, 256, 0, stream>>>(src, dst, pos, E, base8, csr_src);

    int lin_grid = (N_NODES + 31) / 32;

    // layer 1: agg(h16a) + GEMM(mean, x) -> hA (+h16b)
    sage_fused_kernel<<<lin_grid, 256, 0, stream>>>(
        h16a, x, offsets, csr_src, W1l, W1r, b1, hA, h16b,
        (const float*)nullptr, (const float*)nullptr, (float*)nullptr, N_NODES);
    // layer 2: agg(h16b) + GEMM(mean, hA) -> hB (+h16a)
    sage_fused_kernel<<<lin_grid, 256, 0, stream>>>(
        h16b, hA, offsets, csr_src, W2l, W2r, b2, hB, h16a,
        (const float*)nullptr, (const float*)nullptr, (float*)nullptr, N_NODES);
    // layer 3 + classifier: agg(h16a) + GEMM(mean, hB) -> sigmoid(h3 @ Wc + bc)
    sage_fused_kernel<<<lin_grid, 256, 0, stream>>>(
        h16a, hB, offsets, csr_src, W3l, W3r, b3,
        (float*)nullptr, (ushort_t*)nullptr, Wc, bc, out, N_NODES);
}

// Round 8
// 299.226 us; speedup vs baseline: 1.0211x; 1.0211x over previous
//
#include <hip/hip_runtime.h>
#include <hip/hip_bf16.h>
#include <math.h>

#define N_NODES 10000
#define D 128
#define NCOPY 8
#define APAD 132

typedef unsigned int uint_t;
typedef unsigned short ushort_t;

// float -> bf16 bits, round-nearest-even (finite inputs only)
__device__ inline uint_t f2bf_bits(float f) {
    uint_t u = __float_as_uint(f);
    return (u + 0x7fffu + ((u >> 16) & 1u)) >> 16;
}
__device__ inline uint_t pack_bf2(float lo, float hi) {
    return (f2bf_bits(hi) << 16) | f2bf_bits(lo);
}
__device__ inline void acc_bf8(uint4 v, float4& aA, float4& aB) {
    aA.x += __uint_as_float(v.x << 16);
    aA.y += __uint_as_float(v.x & 0xffff0000u);
    aA.z += __uint_as_float(v.y << 16);
    aA.w += __uint_as_float(v.y & 0xffff0000u);
    aB.x += __uint_as_float(v.z << 16);
    aB.y += __uint_as_float(v.z & 0xffff0000u);
    aB.z += __uint_as_float(v.w << 16);
    aB.w += __uint_as_float(v.w & 0xffff0000u);
}

// ---------------- prep: zero deg8 + bf16 mirror of x ----------------
__global__ void prep_kernel(const float* __restrict__ x, ushort_t* __restrict__ h16,
                            uint4* __restrict__ deg8z, int n8, int nz16) {
    int i = blockIdx.x * blockDim.x + threadIdx.x;
    if (i < nz16) deg8z[i] = make_uint4(0u, 0u, 0u, 0u);
    if (i < n8) {
        const float4* p = (const float4*)x + (size_t)i * 2;
        float4 a = p[0], b = p[1];
        uint4 o;
        o.x = pack_bf2(a.x, a.y);
        o.y = pack_bf2(a.z, a.w);
        o.z = pack_bf2(b.x, b.y);
        o.w = pack_bf2(b.z, b.w);
        ((uint4*)h16)[i] = o;
    }
}

// ---------------- CSR build ----------------
__global__ void rank_kernel(const int* __restrict__ dst, int E,
                            int* __restrict__ deg8, int* __restrict__ pos) {
    int i = blockIdx.x * blockDim.x + threadIdx.x;
    if (i < E) {
        int c = blockIdx.x & (NCOPY - 1);
        pos[i] = atomicAdd(&deg8[c * N_NODES + dst[i]], 1);
    }
}

__global__ void sumdeg_kernel(const int* __restrict__ deg8, int* __restrict__ tot, int n) {
    int i = blockIdx.x * blockDim.x + threadIdx.x;
    if (i < n) {
        int s = 0;
#pragma unroll
        for (int c = 0; c < NCOPY; ++c) s += deg8[c * N_NODES + i];
        tot[i] = s;
    }
}

#define SCAN_PER 10
__global__ __launch_bounds__(1024) void scan_kernel(const int* __restrict__ tot,
                                                    int* __restrict__ offsets, int n) {
    __shared__ int wsum[16];
    __shared__ int wpre[16];
    int tid = threadIdx.x;
    int lane = tid & 63, wid = tid >> 6;
    int base = tid * SCAN_PER;
    int loc[SCAN_PER];
    int s = 0;
#pragma unroll
    for (int q = 0; q < SCAN_PER; ++q) {
        int idx = base + q;
        int v = (idx < n) ? tot[idx] : 0;
        s += v;
        loc[q] = s;
    }
    int mysum = s;
#pragma unroll
    for (int off = 1; off < 64; off <<= 1) {
        int t = __shfl_up(s, off, 64);
        if (lane >= off) s += t;
    }
    if (lane == 63) wsum[wid] = s;
    __syncthreads();
    if (wid == 0 && lane < 16) {
        int v = wsum[lane];
        int ss = v;
#pragma unroll
        for (int off = 1; off < 16; off <<= 1) {
            int t = __shfl_up(ss, off, 16);
            if ((lane & 15) >= off) ss += t;
        }
        wpre[lane] = ss - v;
    }
    __syncthreads();
    int thread_excl = wpre[wid] + (s - mysum);
#pragma unroll
    for (int q = 0; q < SCAN_PER; ++q) {
        int idx = base + q;
        if (idx < n) offsets[idx + 1] = thread_excl + loc[q];
    }
    if (tid == 0) offsets[0] = 0;
}

__global__ void base8_kernel(const int* __restrict__ deg8, const int* __restrict__ offsets,
                             int* __restrict__ base8, int n) {
    int i = blockIdx.x * blockDim.x + threadIdx.x;
    if (i < n) {
        int run = offsets[i];
#pragma unroll
        for (int c = 0; c < NCOPY; ++c) {
            base8[c * N_NODES + i] = run;
            run += deg8[c * N_NODES + i];
        }
    }
}

__global__ void csr_write_kernel(const int* __restrict__ src, const int* __restrict__ dst,
                                 const int* __restrict__ pos, int E,
                                 const int* __restrict__ base8, int* __restrict__ csr_src) {
    int i = blockIdx.x * blockDim.x + threadIdx.x;
    if (i < E) {
        int c = (i >> 8) & (NCOPY - 1);  // matches rank_kernel (256 thr/block)
        csr_src[base8[c * N_NODES + dst[i]] + pos[i]] = src[i];
    }
}

// ---------------- fused SAGE layer v2 ----------------
// 512 threads (8 waves), 32 output rows per block, LDS ~50KB -> 3 blocks/CU.
// Phase A: 8 waves x 4 edge-groups gather-mean -> As1; stage fp32 self rows -> As2.
// Phase B: out = relu(As1@W1 + As2@W2 + b), W streamed in K=16 chunks.
// If Wc: fuse classifier sigmoid(row . Wc + bc) -> cls instead of writing out.
__global__ __launch_bounds__(512) void sage_fused_kernel(
        const ushort_t* __restrict__ h16, const float* __restrict__ A2,
        const int* __restrict__ offsets, const int* __restrict__ csr_src,
        const float* __restrict__ W1, const float* __restrict__ W2,
        const float* __restrict__ bias,
        float* __restrict__ out, ushort_t* __restrict__ out16,
        const float* __restrict__ Wc, const float* __restrict__ bcls,
        float* __restrict__ cls, int M) {
    __shared__ float As1[32][APAD];
    __shared__ float As2[32][APAD];
    __shared__ float Ws1[16][D];
    __shared__ float Ws2[16][D];
    int tid = threadIdx.x;
    int r0g = blockIdx.x * 32;

    // ---- stage fp32 self rows (1024 float4, 2 per thread) ----
#pragma unroll
    for (int q = 0; q < 2; ++q) {
        int idx = tid + q * 512;     // 0..1023
        int row = idx >> 5;          // 32 float4 per row
        int col4 = idx & 31;
        int rg = r0g + row;
        float4 v = make_float4(0.f, 0.f, 0.f, 0.f);
        if (rg < M) v = *(const float4*)&A2[rg * D + col4 * 4];
        *(float4*)&As2[row][col4 * 4] = v;
    }

    // ---- aggregate neighbors (bf16 gather) -> As1: wave wv does rows wv*4..wv*4+3 ----
    {
        int wv = tid >> 6;       // 0..7
        int lane = tid & 63;
        int g = lane >> 4;       // edge group 0..3
        int fl = lane & 15;      // feature block (8 bf16)
#pragma unroll
        for (int i = 0; i < 4; ++i) {
            int r = wv * 4 + i;
            int node = r0g + r;
            int beg = 0, end = 0;
            if (node < M) { beg = offsets[node]; end = offsets[node + 1]; }
            float4 aA = make_float4(0.f, 0.f, 0.f, 0.f);
            float4 aB = make_float4(0.f, 0.f, 0.f, 0.f);
#pragma unroll 2
            for (int e = beg + g; e < end; e += 4) {
                int s = csr_src[e];
                uint4 v = *(const uint4*)&h16[s * D + fl * 8];
                acc_bf8(v, aA, aB);
            }
            aA.x += __shfl_xor(aA.x, 16, 64); aA.y += __shfl_xor(aA.y, 16, 64);
            aA.z += __shfl_xor(aA.z, 16, 64); aA.w += __shfl_xor(aA.w, 16, 64);
            aB.x += __shfl_xor(aB.x, 16, 64); aB.y += __shfl_xor(aB.y, 16, 64);
            aB.z += __shfl_xor(aB.z, 16, 64); aB.w += __shfl_xor(aB.w, 16, 64);
            aA.x += __shfl_xor(aA.x, 32, 64); aA.y += __shfl_xor(aA.y, 32, 64);
            aA.z += __shfl_xor(aA.z, 32, 64); aA.w += __shfl_xor(aA.w, 32, 64);
            aB.x += __shfl_xor(aB.x, 32, 64); aB.y += __shfl_xor(aB.y, 32, 64);
            aB.z += __shfl_xor(aB.z, 32, 64); aB.w += __shfl_xor(aB.w, 32, 64);
            if (lane < 16) {
                int cnt = end - beg;
                float inv = (cnt > 0) ? (1.0f / (float)cnt) : 0.f;
                aA.x *= inv; aA.y *= inv; aA.z *= inv; aA.w *= inv;
                aB.x *= inv; aB.y *= inv; aB.z *= inv; aB.w *= inv;
                *(float4*)&As1[r][fl * 8] = aA;
                *(float4*)&As1[r][fl * 8 + 4] = aB;
            }
        }
    }

    int ty = tid >> 4;       // row 0..31
    int tx = tid & 15;
    int c0 = tx * 8;

    float4 b_lo = *(const float4*)&bias[c0];
    float4 b_hi = *(const float4*)&bias[c0 + 4];

    float4 accl = make_float4(0.f, 0.f, 0.f, 0.f);
    float4 acch = make_float4(0.f, 0.f, 0.f, 0.f);

    for (int kc = 0; kc < 8; ++kc) {
        __syncthreads();   // kc=0 also covers As1/As2 staging; later: protects Ws reuse
        {
            int wrow = tid >> 5;          // 0..15
            int col4 = tid & 31;
            int grow = kc * 16 + wrow;
            *(float4*)&Ws1[wrow][col4 * 4] = *(const float4*)&W1[grow * D + col4 * 4];
            *(float4*)&Ws2[wrow][col4 * 4] = *(const float4*)&W2[grow * D + col4 * 4];
        }
        __syncthreads();

#pragma unroll
        for (int kk = 0; kk < 16; ++kk) {
            int k = kc * 16 + kk;
            float a1 = As1[ty][k];
            float a2 = As2[ty][k];
            float4 w1l = *(const float4*)&Ws1[kk][c0];
            float4 w1h = *(const float4*)&Ws1[kk][c0 + 4];
            float4 w2l = *(const float4*)&Ws2[kk][c0];
            float4 w2h = *(const float4*)&Ws2[kk][c0 + 4];
            accl.x += a1 * w1l.x + a2 * w2l.x;
            accl.y += a1 * w1l.y + a2 * w2l.y;
            accl.z += a1 * w1l.z + a2 * w2l.z;
            accl.w += a1 * w1l.w + a2 * w2l.w;
            acch.x += a1 * w1h.x + a2 * w2h.x;
            acch.y += a1 * w1h.y + a2 * w2h.y;
            acch.z += a1 * w1h.z + a2 * w2h.z;
            acch.w += a1 * w1h.w + a2 * w2h.w;
        }
    }

    int rg = r0g + ty;
    float4 vl, vh;
    vl.x = fmaxf(accl.x + b_lo.x, 0.f); vl.y = fmaxf(accl.y + b_lo.y, 0.f);
    vl.z = fmaxf(accl.z + b_lo.z, 0.f); vl.w = fmaxf(accl.w + b_lo.w, 0.f);
    vh.x = fmaxf(acch.x + b_hi.x, 0.f); vh.y = fmaxf(acch.y + b_hi.y, 0.f);
    vh.z = fmaxf(acch.z + b_hi.z, 0.f); vh.w = fmaxf(acch.w + b_hi.w, 0.f);

    if (Wc) {
        float4 wl = *(const float4*)&Wc[c0];
        float4 wh = *(const float4*)&Wc[c0 + 4];
        float p = vl.x * wl.x + vl.y * wl.y + vl.z * wl.z + vl.w * wl.w
                + vh.x * wh.x + vh.y * wh.y + vh.z * wh.z + vh.w * wh.w;
#pragma unroll
        for (int off = 1; off <= 8; off <<= 1) p += __shfl_xor(p, off, 64);
        if (tx == 0 && rg < M) cls[rg] = 1.0f / (1.0f + expf(-(p + bcls[0])));
    } else if (rg < M) {
        *(float4*)&out[rg * D + c0] = vl;
        *(float4*)&out[rg * D + c0 + 4] = vh;
        if (out16) {
            uint4 o;
            o.x = pack_bf2(vl.x, vl.y); o.y = pack_bf2(vl.z, vl.w);
            o.z = pack_bf2(vh.x, vh.y); o.w = pack_bf2(vh.z, vh.w);
            *(uint4*)&out16[rg * D + c0] = o;
        }
    }
}

extern "C" void kernel_launch(void* const* d_in, const int* in_sizes, int n_in,
                              void* d_out, int out_size, void* d_ws, size_t ws_size,
                              hipStream_t stream) {
    const float* x   = (const float*)d_in[0];
    const int* eidx  = (const int*)d_in[1];
    int E = in_sizes[1] / 2;
    const int* src = eidx;
    const int* dst = eidx + E;
    const float* W1l = (const float*)d_in[2];
    const float* b1  = (const float*)d_in[3];
    const float* W1r = (const float*)d_in[4];
    const float* W2l = (const float*)d_in[5];
    const float* b2  = (const float*)d_in[6];
    const float* W2r = (const float*)d_in[7];
    const float* W3l = (const float*)d_in[8];
    const float* b3  = (const float*)d_in[9];
    const float* W3r = (const float*)d_in[10];
    const float* Wc  = (const float*)d_in[11];
    const float* bc  = (const float*)d_in[12];
    float* out = (float*)d_out;

    // workspace carve-up
    char* p = (char*)d_ws;
    int* deg8      = (int*)p;  p += (size_t)NCOPY * N_NODES * 4;
    int* base8     = (int*)p;  p += (size_t)NCOPY * N_NODES * 4;
    int* offsets   = (int*)p;  p += 40960;
    int* tot       = (int*)p;  p += 40960;
    int* csr_src   = (int*)p;  p += (size_t)E * 4;
    int* pos       = (int*)p;  p += (size_t)E * 4;
    float* hA      = (float*)p; p += (size_t)N_NODES * D * 4;
    float* hB      = (float*)p; p += (size_t)N_NODES * D * 4;
    ushort_t* h16a = (ushort_t*)p; p += (size_t)N_NODES * D * 2;
    ushort_t* h16b = (ushort_t*)p; p += (size_t)N_NODES * D * 2;

    int n8 = N_NODES * D / 8;                  // 160000 f2bf items
    int nz16 = (NCOPY * N_NODES * 4) / 16;     // 20000 zero items
    prep_kernel<<<(n8 + 255) / 256, 256, 0, stream>>>(x, h16a, (uint4*)deg8, n8, nz16);

    int eb = (E + 255) / 256;
    int nb = (N_NODES + 255) / 256;
    rank_kernel<<<eb, 256, 0, stream>>>(dst, E, deg8, pos);
    sumdeg_kernel<<<nb, 256, 0, stream>>>(deg8, tot, N_NODES);
    scan_kernel<<<1, 1024, 0, stream>>>(tot, offsets, N_NODES);
    base8_kernel<<<nb, 256, 0, stream>>>(deg8, offsets, base8, N_NODES);
    csr_write_kernel<<<eb, 256, 0, stream>>>(src, dst, pos, E, base8, csr_src);

    int lin_grid = (N_NODES + 31) / 32;

    // layer 1: agg(h16a) + GEMM(mean, x) -> hA (+h16b)
    sage_fused_kernel<<<lin_grid, 512, 0, stream>>>(
        h16a, x, offsets, csr_src, W1l, W1r, b1, hA, h16b,
        (const float*)nullptr, (const float*)nullptr, (float*)nullptr, N_NODES);
    // layer 2: agg(h16b) + GEMM(mean, hA) -> hB (+h16a)
    sage_fused_kernel<<<lin_grid, 512, 0, stream>>>(
        h16b, hA, offsets, csr_src, W2l, W2r, b2, hB, h16a,
        (const float*)nullptr, (const float*)nullptr, (float*)nullptr, N_NODES);
    // layer 3 + classifier
    sage_fused_kernel<<<lin_grid, 512, 0, stream>>>(
        h16a, hB, offsets, csr_src, W3l, W3r, b3,
        (float*)nullptr, (ushort_t*)nullptr, Wc, bc, out, N_NODES);
}

// Round 9
// 194.540 us; speedup vs baseline: 1.5705x; 1.5381x over previous
//
#include <hip/hip_runtime.h>
#include <hip/hip_bf16.h>
#include <math.h>

#define N_NODES 10000
#define D 128
#define NCOPY 8
#define APAD 132

typedef unsigned int uint_t;
typedef unsigned short ushort_t;

__device__ inline uint_t f2bf_bits(float f) {
    uint_t u = __float_as_uint(f);
    return (u + 0x7fffu + ((u >> 16) & 1u)) >> 16;
}
__device__ inline uint_t pack_bf2(float lo, float hi) {
    return (f2bf_bits(hi) << 16) | f2bf_bits(lo);
}
__device__ inline void acc_bf8(uint4 v, float4& aA, float4& aB) {
    aA.x += __uint_as_float(v.x << 16);
    aA.y += __uint_as_float(v.x & 0xffff0000u);
    aA.z += __uint_as_float(v.y << 16);
    aA.w += __uint_as_float(v.y & 0xffff0000u);
    aB.x += __uint_as_float(v.z << 16);
    aB.y += __uint_as_float(v.z & 0xffff0000u);
    aB.z += __uint_as_float(v.w << 16);
    aB.w += __uint_as_float(v.w & 0xffff0000u);
}

// ---------------- prep: zero deg8 + bf16 mirror of x ----------------
__global__ void prep_kernel(const float* __restrict__ x, ushort_t* __restrict__ h16,
                            uint4* __restrict__ deg8z, int n8, int nz16) {
    int i = blockIdx.x * blockDim.x + threadIdx.x;
    if (i < nz16) deg8z[i] = make_uint4(0u, 0u, 0u, 0u);
    if (i < n8) {
        const float4* p = (const float4*)x + (size_t)i * 2;
        float4 a = p[0], b = p[1];
        uint4 o;
        o.x = pack_bf2(a.x, a.y);
        o.y = pack_bf2(a.z, a.w);
        o.z = pack_bf2(b.x, b.y);
        o.w = pack_bf2(b.z, b.w);
        ((uint4*)h16)[i] = o;
    }
}

// ---------------- CSR build ----------------
__global__ void rank_kernel(const int* __restrict__ dst, int E,
                            int* __restrict__ deg8, int* __restrict__ pos) {
    int i = blockIdx.x * blockDim.x + threadIdx.x;
    if (i < E) {
        int c = blockIdx.x & (NCOPY - 1);
        pos[i] = atomicAdd(&deg8[c * N_NODES + dst[i]], 1);
    }
}

__global__ void sumdeg_kernel(const int* __restrict__ deg8, int* __restrict__ tot, int n) {
    int i = blockIdx.x * blockDim.x + threadIdx.x;
    if (i < n) {
        int s = 0;
#pragma unroll
        for (int c = 0; c < NCOPY; ++c) s += deg8[c * N_NODES + i];
        tot[i] = s;
    }
}

#define SCAN_PER 10
__global__ __launch_bounds__(1024) void scan_kernel(const int* __restrict__ tot,
                                                    int* __restrict__ offsets, int n) {
    __shared__ int wsum[16];
    __shared__ int wpre[16];
    int tid = threadIdx.x;
    int lane = tid & 63, wid = tid >> 6;
    int base = tid * SCAN_PER;
    int loc[SCAN_PER];
    int s = 0;
#pragma unroll
    for (int q = 0; q < SCAN_PER; ++q) {
        int idx = base + q;
        int v = (idx < n) ? tot[idx] : 0;
        s += v;
        loc[q] = s;
    }
    int mysum = s;
#pragma unroll
    for (int off = 1; off < 64; off <<= 1) {
        int t = __shfl_up(s, off, 64);
        if (lane >= off) s += t;
    }
    if (lane == 63) wsum[wid] = s;
    __syncthreads();
    if (wid == 0 && lane < 16) {
        int v = wsum[lane];
        int ss = v;
#pragma unroll
        for (int off = 1; off < 16; off <<= 1) {
            int t = __shfl_up(ss, off, 16);
            if ((lane & 15) >= off) ss += t;
        }
        wpre[lane] = ss - v;
    }
    __syncthreads();
    int thread_excl = wpre[wid] + (s - mysum);
#pragma unroll
    for (int q = 0; q < SCAN_PER; ++q) {
        int idx = base + q;
        if (idx < n) offsets[idx + 1] = thread_excl + loc[q];
    }
    if (tid == 0) offsets[0] = 0;
}

__global__ void base8_kernel(const int* __restrict__ deg8, const int* __restrict__ offsets,
                             int* __restrict__ base8, int n) {
    int i = blockIdx.x * blockDim.x + threadIdx.x;
    if (i < n) {
        int run = offsets[i];
#pragma unroll
        for (int c = 0; c < NCOPY; ++c) {
            base8[c * N_NODES + i] = run;
            run += deg8[c * N_NODES + i];
        }
    }
}

__global__ void csr_write_kernel(const int* __restrict__ src, const int* __restrict__ dst,
                                 const int* __restrict__ pos, int E,
                                 const int* __restrict__ base8, int* __restrict__ csr_src) {
    int i = blockIdx.x * blockDim.x + threadIdx.x;
    if (i < E) {
        int c = (i >> 8) & (NCOPY - 1);  // matches rank_kernel (256 thr/block)
        csr_src[base8[c * N_NODES + dst[i]] + pos[i]] = src[i];
    }
}

// ---------------- aggregation (segment mean, bf16 gather) ----------------
// 256 threads per node: 16 edge-groups x 16 lanes; lane covers 8 features (16B).
// Serial chain per group: deg/16 iterations (~4 for avg deg 64).
__global__ __launch_bounds__(256) void aggregate_kernel(const ushort_t* __restrict__ h16,
                                                        const int* __restrict__ offsets,
                                                        const int* __restrict__ csr_src,
                                                        float* __restrict__ mean) {
    __shared__ float tmp[3][16][8];
    int node = blockIdx.x;
    int tid = threadIdx.x;
    int g = tid >> 4;          // 0..15 edge group
    int fl = tid & 15;         // feature block (8 bf16 = 16B)
    int beg = offsets[node], end = offsets[node + 1];
    float4 aA = make_float4(0.f, 0.f, 0.f, 0.f);
    float4 aB = make_float4(0.f, 0.f, 0.f, 0.f);
    for (int e = beg + g; e < end; e += 16) {
        int s = csr_src[e];
        uint4 v = *(const uint4*)&h16[s * D + fl * 8];
        acc_bf8(v, aA, aB);
    }
    // reduce across the 4 edge-groups within each wave (lane bits 4,5)
    aA.x += __shfl_xor(aA.x, 16, 64); aA.y += __shfl_xor(aA.y, 16, 64);
    aA.z += __shfl_xor(aA.z, 16, 64); aA.w += __shfl_xor(aA.w, 16, 64);
    aB.x += __shfl_xor(aB.x, 16, 64); aB.y += __shfl_xor(aB.y, 16, 64);
    aB.z += __shfl_xor(aB.z, 16, 64); aB.w += __shfl_xor(aB.w, 16, 64);
    aA.x += __shfl_xor(aA.x, 32, 64); aA.y += __shfl_xor(aA.y, 32, 64);
    aA.z += __shfl_xor(aA.z, 32, 64); aA.w += __shfl_xor(aA.w, 32, 64);
    aB.x += __shfl_xor(aB.x, 32, 64); aB.y += __shfl_xor(aB.y, 32, 64);
    aB.z += __shfl_xor(aB.z, 32, 64); aB.w += __shfl_xor(aB.w, 32, 64);
    int wv = tid >> 6;
    int lane = tid & 63;
    if (wv > 0 && lane < 16) {
        *(float4*)&tmp[wv - 1][lane][0] = aA;
        *(float4*)&tmp[wv - 1][lane][4] = aB;
    }
    __syncthreads();
    if (tid < 16) {
#pragma unroll
        for (int w = 0; w < 3; ++w) {
            float4 oA = *(const float4*)&tmp[w][tid][0];
            float4 oB = *(const float4*)&tmp[w][tid][4];
            aA.x += oA.x; aA.y += oA.y; aA.z += oA.z; aA.w += oA.w;
            aB.x += oB.x; aB.y += oB.y; aB.z += oB.z; aB.w += oB.w;
        }
        int cnt = end - beg;
        float inv = (cnt > 0) ? (1.0f / (float)cnt) : 0.f;
        aA.x *= inv; aA.y *= inv; aA.z *= inv; aA.w *= inv;
        aB.x *= inv; aB.y *= inv; aB.z *= inv; aB.w *= inv;
        *(float4*)&mean[node * D + tid * 8] = aA;
        *(float4*)&mean[node * D + tid * 8 + 4] = aB;
    }
}

// ---------------- fused SAGE linear: out = relu(A1@W1 + A2@W2 + b) ----------------
// 32 rows x 128 cols per block, 256 threads, 2 rows x 8 cols per thread.
// Optional bf16 mirror; optional fused classifier (layer 3).
__global__ __launch_bounds__(256) void sage_linear_kernel(
        const float* __restrict__ A1, const float* __restrict__ A2,
        const float* __restrict__ W1, const float* __restrict__ W2,
        const float* __restrict__ bias, float* __restrict__ out,
        ushort_t* __restrict__ out16,
        const float* __restrict__ Wc, const float* __restrict__ bcls,
        float* __restrict__ cls, int M) {
    __shared__ float As1[32][APAD];
    __shared__ float As2[32][APAD];
    __shared__ float Ws1[32][D];
    __shared__ float Ws2[32][D];
    int tid = threadIdx.x;
    int r0g = blockIdx.x * 32;
    int ty = tid >> 4;
    int tx = tid & 15;
    int c0 = tx * 8;
    int rl0 = ty, rl1 = ty + 16;

    {
        int row = tid >> 3;
        int rg = r0g + row;
        bool ok = rg < M;
#pragma unroll
        for (int q = 0; q < 4; ++q) {
            int col = ((tid & 7) + q * 8) * 4;
            float4 a1 = make_float4(0.f, 0.f, 0.f, 0.f);
            float4 a2 = make_float4(0.f, 0.f, 0.f, 0.f);
            if (ok) {
                a1 = *(const float4*)&A1[rg * D + col];
                a2 = *(const float4*)&A2[rg * D + col];
            }
            *(float4*)&As1[row][col] = a1;
            *(float4*)&As2[row][col] = a2;
        }
    }

    float4 b_lo = *(const float4*)&bias[c0];
    float4 b_hi = *(const float4*)&bias[c0 + 4];

    float4 acc0l = make_float4(0.f, 0.f, 0.f, 0.f);
    float4 acc0h = make_float4(0.f, 0.f, 0.f, 0.f);
    float4 acc1l = make_float4(0.f, 0.f, 0.f, 0.f);
    float4 acc1h = make_float4(0.f, 0.f, 0.f, 0.f);

    for (int kc = 0; kc < 4; ++kc) {
        __syncthreads();
        {
            int wrow = tid >> 3;
            int grow = kc * 32 + wrow;
#pragma unroll
            for (int q = 0; q < 4; ++q) {
                int col = ((tid & 7) + q * 8) * 4;
                float4 w1 = *(const float4*)&W1[grow * D + col];
                float4 w2 = *(const float4*)&W2[grow * D + col];
                *(float4*)&Ws1[wrow][col] = w1;
                *(float4*)&Ws2[wrow][col] = w2;
            }
        }
        __syncthreads();

#pragma unroll 4
        for (int kk = 0; kk < 32; ++kk) {
            int k = kc * 32 + kk;
            float a10 = As1[rl0][k];
            float a11 = As1[rl1][k];
            float a20 = As2[rl0][k];
            float a21 = As2[rl1][k];
            float4 w1l = *(const float4*)&Ws1[kk][c0];
            float4 w1h = *(const float4*)&Ws1[kk][c0 + 4];
            float4 w2l = *(const float4*)&Ws2[kk][c0];
            float4 w2h = *(const float4*)&Ws2[kk][c0 + 4];
            acc0l.x += a10 * w1l.x + a20 * w2l.x;
            acc0l.y += a10 * w1l.y + a20 * w2l.y;
            acc0l.z += a10 * w1l.z + a20 * w2l.z;
            acc0l.w += a10 * w1l.w + a20 * w2l.w;
            acc0h.x += a10 * w1h.x + a20 * w2h.x;
            acc0h.y += a10 * w1h.y + a20 * w2h.y;
            acc0h.z += a10 * w1h.z + a20 * w2h.z;
            acc0h.w += a10 * w1h.w + a20 * w2h.w;
            acc1l.x += a11 * w1l.x + a21 * w2l.x;
            acc1l.y += a11 * w1l.y + a21 * w2l.y;
            acc1l.z += a11 * w1l.z + a21 * w2l.z;
            acc1l.w += a11 * w1l.w + a21 * w2l.w;
            acc1h.x += a11 * w1h.x + a21 * w2h.x;
            acc1h.y += a11 * w1h.y + a21 * w2h.y;
            acc1h.z += a11 * w1h.z + a21 * w2h.z;
            acc1h.w += a11 * w1h.w + a21 * w2h.w;
        }
    }

    int rg0 = r0g + rl0;
    int rg1 = r0g + rl1;
    float4 vl0, vh0, vl1, vh1;
    vl0.x = fmaxf(acc0l.x + b_lo.x, 0.f); vl0.y = fmaxf(acc0l.y + b_lo.y, 0.f);
    vl0.z = fmaxf(acc0l.z + b_lo.z, 0.f); vl0.w = fmaxf(acc0l.w + b_lo.w, 0.f);
    vh0.x = fmaxf(acc0h.x + b_hi.x, 0.f); vh0.y = fmaxf(acc0h.y + b_hi.y, 0.f);
    vh0.z = fmaxf(acc0h.z + b_hi.z, 0.f); vh0.w = fmaxf(acc0h.w + b_hi.w, 0.f);
    vl1.x = fmaxf(acc1l.x + b_lo.x, 0.f); vl1.y = fmaxf(acc1l.y + b_lo.y, 0.f);
    vl1.z = fmaxf(acc1l.z + b_lo.z, 0.f); vl1.w = fmaxf(acc1l.w + b_lo.w, 0.f);
    vh1.x = fmaxf(acc1h.x + b_hi.x, 0.f); vh1.y = fmaxf(acc1h.y + b_hi.y, 0.f);
    vh1.z = fmaxf(acc1h.z + b_hi.z, 0.f); vh1.w = fmaxf(acc1h.w + b_hi.w, 0.f);

    if (Wc) {
        float4 wl = *(const float4*)&Wc[c0];
        float4 wh = *(const float4*)&Wc[c0 + 4];
        float p0 = vl0.x * wl.x + vl0.y * wl.y + vl0.z * wl.z + vl0.w * wl.w
                 + vh0.x * wh.x + vh0.y * wh.y + vh0.z * wh.z + vh0.w * wh.w;
        float p1 = vl1.x * wl.x + vl1.y * wl.y + vl1.z * wl.z + vl1.w * wl.w
                 + vh1.x * wh.x + vh1.y * wh.y + vh1.z * wh.z + vh1.w * wh.w;
#pragma unroll
        for (int off = 1; off <= 8; off <<= 1) {
            p0 += __shfl_xor(p0, off, 64);
            p1 += __shfl_xor(p1, off, 64);
        }
        if (tx == 0) {
            float b = bcls[0];
            if (rg0 < M) cls[rg0] = 1.0f / (1.0f + expf(-(p0 + b)));
            if (rg1 < M) cls[rg1] = 1.0f / (1.0f + expf(-(p1 + b)));
        }
    } else {
        if (rg0 < M) {
            *(float4*)&out[rg0 * D + c0] = vl0;
            *(float4*)&out[rg0 * D + c0 + 4] = vh0;
            uint4 o;
            o.x = pack_bf2(vl0.x, vl0.y); o.y = pack_bf2(vl0.z, vl0.w);
            o.z = pack_bf2(vh0.x, vh0.y); o.w = pack_bf2(vh0.z, vh0.w);
            *(uint4*)&out16[rg0 * D + c0] = o;
        }
        if (rg1 < M) {
            *(float4*)&out[rg1 * D + c0] = vl1;
            *(float4*)&out[rg1 * D + c0 + 4] = vh1;
            uint4 o;
            o.x = pack_bf2(vl1.x, vl1.y); o.y = pack_bf2(vl1.z, vl1.w);
            o.z = pack_bf2(vh1.x, vh1.y); o.w = pack_bf2(vh1.z, vh1.w);
            *(uint4*)&out16[rg1 * D + c0] = o;
        }
    }
}

extern "C" void kernel_launch(void* const* d_in, const int* in_sizes, int n_in,
                              void* d_out, int out_size, void* d_ws, size_t ws_size,
                              hipStream_t stream) {
    const float* x   = (const float*)d_in[0];
    const int* eidx  = (const int*)d_in[1];
    int E = in_sizes[1] / 2;
    const int* src = eidx;
    const int* dst = eidx + E;
    const float* W1l = (const float*)d_in[2];
    const float* b1  = (const float*)d_in[3];
    const float* W1r = (const float*)d_in[4];
    const float* W2l = (const float*)d_in[5];
    const float* b2  = (const float*)d_in[6];
    const float* W2r = (const float*)d_in[7];
    const float* W3l = (const float*)d_in[8];
    const float* b3  = (const float*)d_in[9];
    const float* W3r = (const float*)d_in[10];
    const float* Wc  = (const float*)d_in[11];
    const float* bc  = (const float*)d_in[12];
    float* out = (float*)d_out;

    // workspace carve-up
    char* p = (char*)d_ws;
    int* deg8      = (int*)p;  p += (size_t)NCOPY * N_NODES * 4;
    int* base8     = (int*)p;  p += (size_t)NCOPY * N_NODES * 4;
    int* offsets   = (int*)p;  p += 40960;
    int* tot       = (int*)p;  p += 40960;
    int* csr_src   = (int*)p;  p += (size_t)E * 4;
    int* pos       = (int*)p;  p += (size_t)E * 4;
    float* mean    = (float*)p; p += (size_t)N_NODES * D * 4;
    float* hA      = (float*)p; p += (size_t)N_NODES * D * 4;
    float* hB      = (float*)p; p += (size_t)N_NODES * D * 4;
    ushort_t* h16a = (ushort_t*)p; p += (size_t)N_NODES * D * 2;
    ushort_t* h16b = (ushort_t*)p; p += (size_t)N_NODES * D * 2;

    int n8 = N_NODES * D / 8;
    int nz16 = (NCOPY * N_NODES * 4) / 16;
    prep_kernel<<<(n8 + 255) / 256, 256, 0, stream>>>(x, h16a, (uint4*)deg8, n8, nz16);

    int eb = (E + 255) / 256;
    int nb = (N_NODES + 255) / 256;
    rank_kernel<<<eb, 256, 0, stream>>>(dst, E, deg8, pos);
    sumdeg_kernel<<<nb, 256, 0, stream>>>(deg8, tot, N_NODES);
    scan_kernel<<<1, 1024, 0, stream>>>(tot, offsets, N_NODES);
    base8_kernel<<<nb, 256, 0, stream>>>(deg8, offsets, base8, N_NODES);
    csr_write_kernel<<<eb, 256, 0, stream>>>(src, dst, pos, E, base8, csr_src);

    int lin_grid = (N_NODES + 31) / 32;

    // layer 1: agg(h16a) -> mean; lin(mean, x) -> hA (+h16b)
    aggregate_kernel<<<N_NODES, 256, 0, stream>>>(h16a, offsets, csr_src, mean);
    sage_linear_kernel<<<lin_grid, 256, 0, stream>>>(
        mean, x, W1l, W1r, b1, hA, h16b,
        (const float*)nullptr, (const float*)nullptr, (float*)nullptr, N_NODES);
    // layer 2: agg(h16b) -> mean; lin(mean, hA) -> hB (+h16a)
    aggregate_kernel<<<N_NODES, 256, 0, stream>>>(h16b, offsets, csr_src, mean);
    sage_linear_kernel<<<lin_grid, 256, 0, stream>>>(
        mean, hA, W2l, W2r, b2, hB, h16a,
        (const float*)nullptr, (const float*)nullptr, (float*)nullptr, N_NODES);
    // layer 3: agg(h16a) -> mean; lin(mean, hB) + classifier -> out
    aggregate_kernel<<<N_NODES, 256, 0, stream>>>(h16a, offsets, csr_src, mean);
    sage_linear_kernel<<<lin_grid, 256, 0, stream>>>(
        mean, hB, W3l, W3r, b3, (float*)nullptr, (ushort_t*)nullptr,
        Wc, bc, out, N_NODES);
}

// Round 11
// 138.662 us; speedup vs baseline: 2.2034x; 1.4030x over previous
//
#include <hip/hip_runtime.h>
#include <hip/hip_fp16.h>
#include <math.h>

#define N_NODES 10000
#define D 128
#define NCOPY 8

typedef unsigned int uint_t;
typedef unsigned short ushort_t;
typedef __attribute__((ext_vector_type(8))) _Float16 f16x8;
typedef __attribute__((ext_vector_type(4))) float f32x4;

#define MFMA16(a, b, c) __builtin_amdgcn_mfma_f32_16x16x32_f16((a), (b), (c), 0, 0, 0)

__device__ inline uint_t pack_h2(float lo, float hi) {
    __half2 h = __floats2half2_rn(lo, hi);
    return *(uint_t*)&h;
}
__device__ inline void acc_h8(uint4 v, float4& aA, float4& aB) {
    float2 f;
    f = __half22float2(*(__half2*)&v.x); aA.x += f.x; aA.y += f.y;
    f = __half22float2(*(__half2*)&v.y); aA.z += f.x; aA.w += f.y;
    f = __half22float2(*(__half2*)&v.z); aB.x += f.x; aB.y += f.y;
    f = __half22float2(*(__half2*)&v.w); aB.z += f.x; aB.w += f.y;
}

// ---------------- prep: zero deg8 + fp16 mirror of x + W^T fp16 ----------------
__global__ void prep_kernel(const float* __restrict__ x, __half* __restrict__ xm,
                            const float* __restrict__ W1l, const float* __restrict__ W1r,
                            const float* __restrict__ W2l, const float* __restrict__ W2r,
                            const float* __restrict__ W3l, const float* __restrict__ W3r,
                            __half* __restrict__ WT,
                            uint4* __restrict__ deg8z, int n8, int nz16, int nwt) {
    int i = blockIdx.x * blockDim.x + threadIdx.x;
    if (i < nz16) deg8z[i] = make_uint4(0u, 0u, 0u, 0u);
    if (i < n8) {
        const float4* p = (const float4*)x + (size_t)i * 2;
        float4 a = p[0], b = p[1];
        uint4 o;
        o.x = pack_h2(a.x, a.y); o.y = pack_h2(a.z, a.w);
        o.z = pack_h2(b.x, b.y); o.w = pack_h2(b.z, b.w);
        ((uint4*)xm)[i] = o;
    }
    if (i < nwt) {
        int m = i >> 14, idx = i & 16383;
        int n = idx >> 7, k = idx & 127;
        const float* Wm = (m == 0) ? W1l : (m == 1) ? W1r : (m == 2) ? W2l
                        : (m == 3) ? W2r : (m == 4) ? W3l : W3r;
        WT[i] = __float2half_rn(Wm[k * D + n]);   // WT[m][n][k] = W[k][n]
    }
}

// ---------------- CSR build ----------------
__global__ void rank_kernel(const int* __restrict__ dst, int E,
                            int* __restrict__ deg8, int* __restrict__ pos) {
    int i = blockIdx.x * blockDim.x + threadIdx.x;
    if (i < E) {
        int c = blockIdx.x & (NCOPY - 1);
        pos[i] = atomicAdd(&deg8[c * N_NODES + dst[i]], 1);
    }
}

__global__ void sumdeg_kernel(const int* __restrict__ deg8, int* __restrict__ tot, int n) {
    int i = blockIdx.x * blockDim.x + threadIdx.x;
    if (i < n) {
        int s = 0;
#pragma unroll
        for (int c = 0; c < NCOPY; ++c) s += deg8[c * N_NODES + i];
        tot[i] = s;
    }
}

#define SCAN_PER 10
__global__ __launch_bounds__(1024) void scan_kernel(const int* __restrict__ tot,
                                                    int* __restrict__ offsets, int n) {
    __shared__ int wsum[16];
    __shared__ int wpre[16];
    int tid = threadIdx.x;
    int lane = tid & 63, wid = tid >> 6;
    int base = tid * SCAN_PER;
    int loc[SCAN_PER];
    int s = 0;
#pragma unroll
    for (int q = 0; q < SCAN_PER; ++q) {
        int idx = base + q;
        int v = (idx < n) ? tot[idx] : 0;
        s += v;
        loc[q] = s;
    }
    int mysum = s;
#pragma unroll
    for (int off = 1; off < 64; off <<= 1) {
        int t = __shfl_up(s, off, 64);
        if (lane >= off) s += t;
    }
    if (lane == 63) wsum[wid] = s;
    __syncthreads();
    if (wid == 0 && lane < 16) {
        int v = wsum[lane];
        int ss = v;
#pragma unroll
        for (int off = 1; off < 16; off <<= 1) {
            int t = __shfl_up(ss, off, 16);
            if ((lane & 15) >= off) ss += t;
        }
        wpre[lane] = ss - v;
    }
    __syncthreads();
    int thread_excl = wpre[wid] + (s - mysum);
#pragma unroll
    for (int q = 0; q < SCAN_PER; ++q) {
        int idx = base + q;
        if (idx < n) offsets[idx + 1] = thread_excl + loc[q];
    }
    if (tid == 0) offsets[0] = 0;
}

__global__ void base8_kernel(const int* __restrict__ deg8, const int* __restrict__ offsets,
                             int* __restrict__ base8, int n) {
    int i = blockIdx.x * blockDim.x + threadIdx.x;
    if (i < n) {
        int run = offsets[i];
#pragma unroll
        for (int c = 0; c < NCOPY; ++c) {
            base8[c * N_NODES + i] = run;
            run += deg8[c * N_NODES + i];
        }
    }
}

__global__ void csr_write_kernel(const int* __restrict__ src, const int* __restrict__ dst,
                                 const int* __restrict__ pos, int E,
                                 const int* __restrict__ base8, int* __restrict__ csr_src) {
    int i = blockIdx.x * blockDim.x + threadIdx.x;
    if (i < E) {
        int c = (i >> 8) & (NCOPY - 1);  // matches rank_kernel (256 thr/block)
        csr_src[base8[c * N_NODES + dst[i]] + pos[i]] = src[i];
    }
}

// ---------------- aggregation (segment mean, fp16 gather -> fp16 mean) ----------------
// 256 threads per node: 16 edge-groups x 16 lanes; lane covers 8 features (16B).
__global__ __launch_bounds__(256) void aggregate_kernel(const __half* __restrict__ h16,
                                                        const int* __restrict__ offsets,
                                                        const int* __restrict__ csr_src,
                                                        __half* __restrict__ mean16) {
    __shared__ float tmp[3][16][8];
    int node = blockIdx.x;
    int tid = threadIdx.x;
    int g = tid >> 4;          // 0..15 edge group
    int fl = tid & 15;         // feature block (8 fp16 = 16B)
    int beg = offsets[node], end = offsets[node + 1];
    float4 aA = make_float4(0.f, 0.f, 0.f, 0.f);
    float4 aB = make_float4(0.f, 0.f, 0.f, 0.f);
    for (int e = beg + g; e < end; e += 16) {
        int s = csr_src[e];
        uint4 v = *(const uint4*)&h16[s * D + fl * 8];
        acc_h8(v, aA, aB);
    }
    // reduce across the 4 edge-groups within each wave (lane bits 4,5)
    aA.x += __shfl_xor(aA.x, 16, 64); aA.y += __shfl_xor(aA.y, 16, 64);
    aA.z += __shfl_xor(aA.z, 16, 64); aA.w += __shfl_xor(aA.w, 16, 64);
    aB.x += __shfl_xor(aB.x, 16, 64); aB.y += __shfl_xor(aB.y, 16, 64);
    aB.z += __shfl_xor(aB.z, 16, 64); aB.w += __shfl_xor(aB.w, 16, 64);
    aA.x += __shfl_xor(aA.x, 32, 64); aA.y += __shfl_xor(aA.y, 32, 64);
    aA.z += __shfl_xor(aA.z, 32, 64); aA.w += __shfl_xor(aA.w, 32, 64);
    aB.x += __shfl_xor(aB.x, 32, 64); aB.y += __shfl_xor(aB.y, 32, 64);
    aB.z += __shfl_xor(aB.z, 32, 64); aB.w += __shfl_xor(aB.w, 32, 64);
    int wv = tid >> 6;
    int lane = tid & 63;
    if (wv > 0 && lane < 16) {
        *(float4*)&tmp[wv - 1][lane][0] = aA;
        *(float4*)&tmp[wv - 1][lane][4] = aB;
    }
    __syncthreads();
    if (tid < 16) {
#pragma unroll
        for (int w = 0; w < 3; ++w) {
            float4 oA = *(const float4*)&tmp[w][tid][0];
            float4 oB = *(const float4*)&tmp[w][tid][4];
            aA.x += oA.x; aA.y += oA.y; aA.z += oA.z; aA.w += oA.w;
            aB.x += oB.x; aB.y += oB.y; aB.z += oB.z; aB.w += oB.w;
        }
        int cnt = end - beg;
        float inv = (cnt > 0) ? (1.0f / (float)cnt) : 0.f;
        uint4 o;
        o.x = pack_h2(aA.x * inv, aA.y * inv);
        o.y = pack_h2(aA.z * inv, aA.w * inv);
        o.z = pack_h2(aB.x * inv, aB.y * inv);
        o.w = pack_h2(aB.z * inv, aB.w * inv);
        *(uint4*)&mean16[node * D + tid * 8] = o;
    }
}

// ---------------- MFMA fp16 SAGE linear ----------------
// 16 rows x 128 cols per block, 128 threads (2 waves x 4 col-tiles of 16).
// out = relu(mean16@W1 + self16@W2 + b); layers 1-2 write fp16 mirror;
// layer 3 (Wc != null) fuses classifier sigmoid(row . Wc + bc).
// Fragment layout (16x16x32): A row=l&15,k=(l>>4)*8+j; B col=l&15 same k;
// C row=(l>>4)*4+j, col=l&15.
__global__ __launch_bounds__(128) void lin_mfma_kernel(
        const __half* __restrict__ A1, const __half* __restrict__ A2,
        const __half* __restrict__ BT1, const __half* __restrict__ BT2,
        const float* __restrict__ bias, __half* __restrict__ out16,
        const float* __restrict__ Wc, const float* __restrict__ bcls,
        float* __restrict__ cls) {
    __shared__ float pl[2][16];
    int r0 = blockIdx.x * 16;
    int w  = (int)threadIdx.x >> 6;   // wave 0..1 -> col half
    int l  = (int)threadIdx.x & 63;
    int lr = l & 15;
    int kg = l >> 4;

    const __half* a1p = A1 + (r0 + lr) * D + kg * 8;
    const __half* a2p = A2 + (r0 + lr) * D + kg * 8;
    f16x8 a1f[4], a2f[4];
#pragma unroll
    for (int ko = 0; ko < 4; ++ko) {
        a1f[ko] = *(const f16x8*)(a1p + ko * 32);
        a2f[ko] = *(const f16x8*)(a2p + ko * 32);
    }

    float p0 = 0.f, p1 = 0.f, p2 = 0.f, p3 = 0.f;   // classifier partials (row j=0..3)

#pragma unroll
    for (int ct = 0; ct < 4; ++ct) {
        int c = w * 64 + ct * 16 + lr;               // output column
        const __half* b1p = BT1 + c * D + kg * 8;
        const __half* b2p = BT2 + c * D + kg * 8;
        f32x4 acc = {0.f, 0.f, 0.f, 0.f};
#pragma unroll
        for (int ko = 0; ko < 4; ++ko)
            acc = MFMA16(a1f[ko], *(const f16x8*)(b1p + ko * 32), acc);
#pragma unroll
        for (int ko = 0; ko < 4; ++ko)
            acc = MFMA16(a2f[ko], *(const f16x8*)(b2p + ko * 32), acc);

        float bcol = bias[c];
        float v0 = fmaxf(acc[0] + bcol, 0.f);
        float v1 = fmaxf(acc[1] + bcol, 0.f);
        float v2 = fmaxf(acc[2] + bcol, 0.f);
        float v3 = fmaxf(acc[3] + bcol, 0.f);
        if (Wc) {
            float wc = Wc[c];
            p0 += v0 * wc; p1 += v1 * wc; p2 += v2 * wc; p3 += v3 * wc;
        } else {
            int rbase = (r0 + kg * 4) * D + c;
            out16[rbase]         = __float2half_rn(v0);
            out16[rbase + D]     = __float2half_rn(v1);
            out16[rbase + 2 * D] = __float2half_rn(v2);
            out16[rbase + 3 * D] = __float2half_rn(v3);
        }
    }

    if (Wc) {
        // reduce over the 16 col-lanes (lane bits 0..3)
#pragma unroll
        for (int off = 1; off <= 8; off <<= 1) {
            p0 += __shfl_xor(p0, off, 64);
            p1 += __shfl_xor(p1, off, 64);
            p2 += __shfl_xor(p2, off, 64);
            p3 += __shfl_xor(p3, off, 64);
        }
        if (lr == 0) {
            pl[w][kg * 4 + 0] = p0;
            pl[w][kg * 4 + 1] = p1;
            pl[w][kg * 4 + 2] = p2;
            pl[w][kg * 4 + 3] = p3;
        }
        __syncthreads();
        if (threadIdx.x < 16) {
            float s = pl[0][threadIdx.x] + pl[1][threadIdx.x] + bcls[0];
            cls[r0 + threadIdx.x] = 1.0f / (1.0f + expf(-s));
        }
    }
}

extern "C" void kernel_launch(void* const* d_in, const int* in_sizes, int n_in,
                              void* d_out, int out_size, void* d_ws, size_t ws_size,
                              hipStream_t stream) {
    const float* x   = (const float*)d_in[0];
    const int* eidx  = (const int*)d_in[1];
    int E = in_sizes[1] / 2;
    const int* src = eidx;
    const int* dst = eidx + E;
    const float* W1l = (const float*)d_in[2];
    const float* b1  = (const float*)d_in[3];
    const float* W1r = (const float*)d_in[4];
    const float* W2l = (const float*)d_in[5];
    const float* b2  = (const float*)d_in[6];
    const float* W2r = (const float*)d_in[7];
    const float* W3l = (const float*)d_in[8];
    const float* b3  = (const float*)d_in[9];
    const float* W3r = (const float*)d_in[10];
    const float* Wc  = (const float*)d_in[11];
    const float* bc  = (const float*)d_in[12];
    float* out = (float*)d_out;

    // workspace carve-up
    char* p = (char*)d_ws;
    int* deg8      = (int*)p;   p += (size_t)NCOPY * N_NODES * 4;
    int* base8     = (int*)p;   p += (size_t)NCOPY * N_NODES * 4;
    int* offsets   = (int*)p;   p += 40960;
    int* tot       = (int*)p;   p += 40960;
    int* csr_src   = (int*)p;   p += (size_t)E * 4;
    int* pos       = (int*)p;   p += (size_t)E * 4;
    __half* mean16 = (__half*)p; p += (size_t)N_NODES * D * 2;
    __half* xm     = (__half*)p; p += (size_t)N_NODES * D * 2;
    __half* m1     = (__half*)p; p += (size_t)N_NODES * D * 2;
    __half* m2     = (__half*)p; p += (size_t)N_NODES * D * 2;
    __half* WT     = (__half*)p; p += (size_t)6 * D * D * 2;

    int n8  = N_NODES * D / 8;                 // 160000
    int nz16 = (NCOPY * N_NODES * 4) / 16;     // 20000
    int nwt = 6 * D * D;                       // 98304
    prep_kernel<<<(n8 + 255) / 256, 256, 0, stream>>>(
        x, xm, W1l, W1r, W2l, W2r, W3l, W3r, WT, (uint4*)deg8, n8, nz16, nwt);

    int eb = (E + 255) / 256;
    int nb = (N_NODES + 255) / 256;
    rank_kernel<<<eb, 256, 0, stream>>>(dst, E, deg8, pos);
    sumdeg_kernel<<<nb, 256, 0, stream>>>(deg8, tot, N_NODES);
    scan_kernel<<<1, 1024, 0, stream>>>(tot, offsets, N_NODES);
    base8_kernel<<<nb, 256, 0, stream>>>(deg8, offsets, base8, N_NODES);
    csr_write_kernel<<<eb, 256, 0, stream>>>(src, dst, pos, E, base8, csr_src);

    int lin_grid = N_NODES / 16;   // 625, exact

    // layer 1: agg(xm) -> mean16; mfma(mean16, xm) -> m1
    aggregate_kernel<<<N_NODES, 256, 0, stream>>>(xm, offsets, csr_src, mean16);
    lin_mfma_kernel<<<lin_grid, 128, 0, stream>>>(
        mean16, xm, WT, WT + D * D, b1, m1,
        (const float*)nullptr, (const float*)nullptr, (float*)nullptr);
    // layer 2: agg(m1) -> mean16; mfma(mean16, m1) -> m2
    aggregate_kernel<<<N_NODES, 256, 0, stream>>>(m1, offsets, csr_src, mean16);
    lin_mfma_kernel<<<lin_grid, 128, 0, stream>>>(
        mean16, m1, WT + 2 * D * D, WT + 3 * D * D, b2, m2,
        (const float*)nullptr, (const float*)nullptr, (float*)nullptr);
    // layer 3 + classifier: agg(m2) -> mean16; mfma(mean16, m2) . Wc -> out
    aggregate_kernel<<<N_NODES, 256, 0, stream>>>(m2, offsets, csr_src, mean16);
    lin_mfma_kernel<<<lin_grid, 128, 0, stream>>>(
        mean16, m2, WT + 4 * D * D, WT + 5 * D * D, b3, (__half*)nullptr,
        Wc, bc, out);
}

// Round 12
// 129.362 us; speedup vs baseline: 2.3618x; 1.0719x over previous
//
#include <hip/hip_runtime.h>
#include <hip/hip_fp16.h>
#include <math.h>

#define N_NODES 10000
#define D 128
#define NCOPY 16

typedef unsigned int uint_t;
typedef __attribute__((ext_vector_type(8))) _Float16 f16x8;
typedef __attribute__((ext_vector_type(4))) float f32x4;

#define MFMA16(a, b, c) __builtin_amdgcn_mfma_f32_16x16x32_f16((a), (b), (c), 0, 0, 0)

__device__ inline uint_t pack_h2(float lo, float hi) {
    __half2 h = __floats2half2_rn(lo, hi);
    return *(uint_t*)&h;
}
__device__ inline void acc_h8(uint4 v, float4& aA, float4& aB) {
    float2 f;
    f = __half22float2(*(__half2*)&v.x); aA.x += f.x; aA.y += f.y;
    f = __half22float2(*(__half2*)&v.y); aA.z += f.x; aA.w += f.y;
    f = __half22float2(*(__half2*)&v.z); aB.x += f.x; aB.y += f.y;
    f = __half22float2(*(__half2*)&v.w); aB.z += f.x; aB.w += f.y;
}

// ---------------- prep: zero deg + fp16 mirror of x + W^T fp16 ----------------
__global__ void prep_kernel(const float* __restrict__ x, __half* __restrict__ xm,
                            const float* __restrict__ W1l, const float* __restrict__ W1r,
                            const float* __restrict__ W2l, const float* __restrict__ W2r,
                            const float* __restrict__ W3l, const float* __restrict__ W3r,
                            __half* __restrict__ WT,
                            uint4* __restrict__ degz, int n8, int nz16, int nwt) {
    int i = blockIdx.x * blockDim.x + threadIdx.x;
    if (i < nz16) degz[i] = make_uint4(0u, 0u, 0u, 0u);
    if (i < n8) {
        const float4* p = (const float4*)x + (size_t)i * 2;
        float4 a = p[0], b = p[1];
        uint4 o;
        o.x = pack_h2(a.x, a.y); o.y = pack_h2(a.z, a.w);
        o.z = pack_h2(b.x, b.y); o.w = pack_h2(b.z, b.w);
        ((uint4*)xm)[i] = o;
    }
    if (i < nwt) {
        int m = i >> 14, idx = i & 16383;
        int n = idx >> 7, k = idx & 127;
        const float* Wm = (m == 0) ? W1l : (m == 1) ? W1r : (m == 2) ? W2l
                        : (m == 3) ? W2r : (m == 4) ? W3l : W3r;
        WT[i] = __float2half_rn(Wm[k * D + n]);   // WT[m][n][k] = W[k][n]
    }
}

// ---------------- CSR build ----------------
__global__ void rank_kernel(const int* __restrict__ dst, int E,
                            int* __restrict__ degN, int* __restrict__ pos) {
    int i = blockIdx.x * blockDim.x + threadIdx.x;
    if (i < E) {
        int c = blockIdx.x & (NCOPY - 1);
        pos[i] = atomicAdd(&degN[c * N_NODES + dst[i]], 1);
    }
}

__global__ void sumdeg_kernel(const int* __restrict__ degN, int* __restrict__ tot, int n) {
    int i = blockIdx.x * blockDim.x + threadIdx.x;
    if (i < n) {
        int s = 0;
#pragma unroll
        for (int c = 0; c < NCOPY; ++c) s += degN[c * N_NODES + i];
        tot[i] = s;
    }
}

// single-block scan with LDS-staged coalesced IO: tot[0..n) -> offsets[0..n]
#define SCAN_PER 10
#define SCAN_N 10240
__global__ __launch_bounds__(1024) void scan_kernel(const int* __restrict__ tot,
                                                    int* __restrict__ offsets, int n) {
    __shared__ int buf[SCAN_N];
    __shared__ int wsum[16];
    __shared__ int wpre[16];
    int tid = threadIdx.x;
    int lane = tid & 63, wid = tid >> 6;
    // coalesced load
#pragma unroll
    for (int q = 0; q < SCAN_PER; ++q) {
        int idx = q * 1024 + tid;
        buf[idx] = (idx < n) ? tot[idx] : 0;
    }
    __syncthreads();
    int base = tid * SCAN_PER;
    int loc[SCAN_PER];
    int s = 0;
#pragma unroll
    for (int q = 0; q < SCAN_PER; ++q) {
        s += buf[base + q];
        loc[q] = s;
    }
    int mysum = s;
#pragma unroll
    for (int off = 1; off < 64; off <<= 1) {
        int t = __shfl_up(s, off, 64);
        if (lane >= off) s += t;
    }
    if (lane == 63) wsum[wid] = s;
    __syncthreads();
    if (wid == 0 && lane < 16) {
        int v = wsum[lane];
        int ss = v;
#pragma unroll
        for (int off = 1; off < 16; off <<= 1) {
            int t = __shfl_up(ss, off, 16);
            if ((lane & 15) >= off) ss += t;
        }
        wpre[lane] = ss - v;
    }
    __syncthreads();
    int thread_excl = wpre[wid] + (s - mysum);
#pragma unroll
    for (int q = 0; q < SCAN_PER; ++q) buf[base + q] = thread_excl + loc[q];
    __syncthreads();
    // coalesced store
#pragma unroll
    for (int q = 0; q < SCAN_PER; ++q) {
        int idx = q * 1024 + tid;
        if (idx < n) offsets[idx + 1] = buf[idx];
    }
    if (tid == 0) offsets[0] = 0;
}

__global__ void baseN_kernel(const int* __restrict__ degN, const int* __restrict__ offsets,
                             int* __restrict__ baseN, int n) {
    int i = blockIdx.x * blockDim.x + threadIdx.x;
    if (i < n) {
        int run = offsets[i];
#pragma unroll
        for (int c = 0; c < NCOPY; ++c) {
            baseN[c * N_NODES + i] = run;
            run += degN[c * N_NODES + i];
        }
    }
}

__global__ void csr_write_kernel(const int* __restrict__ src, const int* __restrict__ dst,
                                 const int* __restrict__ pos, int E,
                                 const int* __restrict__ baseN, int* __restrict__ csr_src) {
    int i = blockIdx.x * blockDim.x + threadIdx.x;
    if (i < E) {
        int c = (i >> 8) & (NCOPY - 1);  // matches rank_kernel (256 thr/block)
        csr_src[baseN[c * N_NODES + dst[i]] + pos[i]] = src[i];
    }
}

// ---------------- aggregation (segment mean, fp16 gather -> fp16 mean) ----------------
// 256 threads per node: 16 edge-groups x 16 lanes; lane covers 8 features (16B).
// Edge loop unrolled x2 with independent accumulators for ILP.
__global__ __launch_bounds__(256) void aggregate_kernel(const __half* __restrict__ h16,
                                                        const int* __restrict__ offsets,
                                                        const int* __restrict__ csr_src,
                                                        __half* __restrict__ mean16) {
    __shared__ float tmp[3][16][8];
    int node = blockIdx.x;
    int tid = threadIdx.x;
    int g = tid >> 4;          // 0..15 edge group
    int fl = tid & 15;         // feature block (8 fp16 = 16B)
    int beg = offsets[node], end = offsets[node + 1];
    float4 aA = make_float4(0.f, 0.f, 0.f, 0.f);
    float4 aB = make_float4(0.f, 0.f, 0.f, 0.f);
    float4 cA = make_float4(0.f, 0.f, 0.f, 0.f);
    float4 cB = make_float4(0.f, 0.f, 0.f, 0.f);
    int e = beg + g;
    for (; e + 16 < end; e += 32) {
        int s0 = csr_src[e];
        int s1 = csr_src[e + 16];
        uint4 v0 = *(const uint4*)&h16[s0 * D + fl * 8];
        uint4 v1 = *(const uint4*)&h16[s1 * D + fl * 8];
        acc_h8(v0, aA, aB);
        acc_h8(v1, cA, cB);
    }
    if (e < end) {
        int s0 = csr_src[e];
        uint4 v0 = *(const uint4*)&h16[s0 * D + fl * 8];
        acc_h8(v0, aA, aB);
    }
    aA.x += cA.x; aA.y += cA.y; aA.z += cA.z; aA.w += cA.w;
    aB.x += cB.x; aB.y += cB.y; aB.z += cB.z; aB.w += cB.w;
    // reduce across the 4 edge-groups within each wave (lane bits 4,5)
    aA.x += __shfl_xor(aA.x, 16, 64); aA.y += __shfl_xor(aA.y, 16, 64);
    aA.z += __shfl_xor(aA.z, 16, 64); aA.w += __shfl_xor(aA.w, 16, 64);
    aB.x += __shfl_xor(aB.x, 16, 64); aB.y += __shfl_xor(aB.y, 16, 64);
    aB.z += __shfl_xor(aB.z, 16, 64); aB.w += __shfl_xor(aB.w, 16, 64);
    aA.x += __shfl_xor(aA.x, 32, 64); aA.y += __shfl_xor(aA.y, 32, 64);
    aA.z += __shfl_xor(aA.z, 32, 64); aA.w += __shfl_xor(aA.w, 32, 64);
    aB.x += __shfl_xor(aB.x, 32, 64); aB.y += __shfl_xor(aB.y, 32, 64);
    aB.z += __shfl_xor(aB.z, 32, 64); aB.w += __shfl_xor(aB.w, 32, 64);
    int wv = tid >> 6;
    int lane = tid & 63;
    if (wv > 0 && lane < 16) {
        *(float4*)&tmp[wv - 1][lane][0] = aA;
        *(float4*)&tmp[wv - 1][lane][4] = aB;
    }
    __syncthreads();
    if (tid < 16) {
#pragma unroll
        for (int w = 0; w < 3; ++w) {
            float4 oA = *(const float4*)&tmp[w][tid][0];
            float4 oB = *(const float4*)&tmp[w][tid][4];
            aA.x += oA.x; aA.y += oA.y; aA.z += oA.z; aA.w += oA.w;
            aB.x += oB.x; aB.y += oB.y; aB.z += oB.z; aB.w += oB.w;
        }
        int cnt = end - beg;
        float inv = (cnt > 0) ? (1.0f / (float)cnt) : 0.f;
        uint4 o;
        o.x = pack_h2(aA.x * inv, aA.y * inv);
        o.y = pack_h2(aA.z * inv, aA.w * inv);
        o.z = pack_h2(aB.x * inv, aB.y * inv);
        o.w = pack_h2(aB.z * inv, aB.w * inv);
        *(uint4*)&mean16[node * D + tid * 8] = o;
    }
}

// ---------------- MFMA fp16 SAGE linear ----------------
// 16 rows x 128 cols per block, 128 threads (2 waves x 4 col-tiles of 16).
__global__ __launch_bounds__(128) void lin_mfma_kernel(
        const __half* __restrict__ A1, const __half* __restrict__ A2,
        const __half* __restrict__ BT1, const __half* __restrict__ BT2,
        const float* __restrict__ bias, __half* __restrict__ out16,
        const float* __restrict__ Wc, const float* __restrict__ bcls,
        float* __restrict__ cls) {
    __shared__ float pl[2][16];
    int r0 = blockIdx.x * 16;
    int w  = (int)threadIdx.x >> 6;   // wave 0..1 -> col half
    int l  = (int)threadIdx.x & 63;
    int lr = l & 15;
    int kg = l >> 4;

    const __half* a1p = A1 + (r0 + lr) * D + kg * 8;
    const __half* a2p = A2 + (r0 + lr) * D + kg * 8;
    f16x8 a1f[4], a2f[4];
#pragma unroll
    for (int ko = 0; ko < 4; ++ko) {
        a1f[ko] = *(const f16x8*)(a1p + ko * 32);
        a2f[ko] = *(const f16x8*)(a2p + ko * 32);
    }

    float p0 = 0.f, p1 = 0.f, p2 = 0.f, p3 = 0.f;

#pragma unroll
    for (int ct = 0; ct < 4; ++ct) {
        int c = w * 64 + ct * 16 + lr;               // output column
        const __half* b1p = BT1 + c * D + kg * 8;
        const __half* b2p = BT2 + c * D + kg * 8;
        f32x4 acc = {0.f, 0.f, 0.f, 0.f};
#pragma unroll
        for (int ko = 0; ko < 4; ++ko)
            acc = MFMA16(a1f[ko], *(const f16x8*)(b1p + ko * 32), acc);
#pragma unroll
        for (int ko = 0; ko < 4; ++ko)
            acc = MFMA16(a2f[ko], *(const f16x8*)(b2p + ko * 32), acc);

        float bcol = bias[c];
        float v0 = fmaxf(acc[0] + bcol, 0.f);
        float v1 = fmaxf(acc[1] + bcol, 0.f);
        float v2 = fmaxf(acc[2] + bcol, 0.f);
        float v3 = fmaxf(acc[3] + bcol, 0.f);
        if (Wc) {
            float wc = Wc[c];
            p0 += v0 * wc; p1 += v1 * wc; p2 += v2 * wc; p3 += v3 * wc;
        } else {
            int rbase = (r0 + kg * 4) * D + c;
            out16[rbase]         = __float2half_rn(v0);
            out16[rbase + D]     = __float2half_rn(v1);
            out16[rbase + 2 * D] = __float2half_rn(v2);
            out16[rbase + 3 * D] = __float2half_rn(v3);
        }
    }

    if (Wc) {
#pragma unroll
        for (int off = 1; off <= 8; off <<= 1) {
            p0 += __shfl_xor(p0, off, 64);
            p1 += __shfl_xor(p1, off, 64);
            p2 += __shfl_xor(p2, off, 64);
            p3 += __shfl_xor(p3, off, 64);
        }
        if (lr == 0) {
            pl[w][kg * 4 + 0] = p0;
            pl[w][kg * 4 + 1] = p1;
            pl[w][kg * 4 + 2] = p2;
            pl[w][kg * 4 + 3] = p3;
        }
        __syncthreads();
        if (threadIdx.x < 16) {
            float s = pl[0][threadIdx.x] + pl[1][threadIdx.x] + bcls[0];
            cls[r0 + threadIdx.x] = 1.0f / (1.0f + expf(-s));
        }
    }
}

extern "C" void kernel_launch(void* const* d_in, const int* in_sizes, int n_in,
                              void* d_out, int out_size, void* d_ws, size_t ws_size,
                              hipStream_t stream) {
    const float* x   = (const float*)d_in[0];
    const int* eidx  = (const int*)d_in[1];
    int E = in_sizes[1] / 2;
    const int* src = eidx;
    const int* dst = eidx + E;
    const float* W1l = (const float*)d_in[2];
    const float* b1  = (const float*)d_in[3];
    const float* W1r = (const float*)d_in[4];
    const float* W2l = (const float*)d_in[5];
    const float* b2  = (const float*)d_in[6];
    const float* W2r = (const float*)d_in[7];
    const float* W3l = (const float*)d_in[8];
    const float* b3  = (const float*)d_in[9];
    const float* W3r = (const float*)d_in[10];
    const float* Wc  = (const float*)d_in[11];
    const float* bc  = (const float*)d_in[12];
    float* out = (float*)d_out;

    // workspace carve-up
    char* p = (char*)d_ws;
    int* degN      = (int*)p;   p += (size_t)NCOPY * N_NODES * 4;   // 640000
    int* baseN     = (int*)p;   p += (size_t)NCOPY * N_NODES * 4;
    int* offsets   = (int*)p;   p += 40960;
    int* tot       = (int*)p;   p += 40960;
    int* csr_src   = (int*)p;   p += (size_t)E * 4;
    int* pos       = (int*)p;   p += (size_t)E * 4;
    __half* mean16 = (__half*)p; p += (size_t)N_NODES * D * 2;
    __half* xm     = (__half*)p; p += (size_t)N_NODES * D * 2;
    __half* m1     = (__half*)p; p += (size_t)N_NODES * D * 2;
    __half* m2     = (__half*)p; p += (size_t)N_NODES * D * 2;
    __half* WT     = (__half*)p; p += (size_t)6 * D * D * 2;

    int n8  = N_NODES * D / 8;                 // 160000
    int nz16 = (NCOPY * N_NODES * 4) / 16;     // 40000
    int nwt = 6 * D * D;                       // 98304
    prep_kernel<<<(n8 + 255) / 256, 256, 0, stream>>>(
        x, xm, W1l, W1r, W2l, W2r, W3l, W3r, WT, (uint4*)degN, n8, nz16, nwt);

    int eb = (E + 255) / 256;
    int nb = (N_NODES + 255) / 256;
    rank_kernel<<<eb, 256, 0, stream>>>(dst, E, degN, pos);
    sumdeg_kernel<<<nb, 256, 0, stream>>>(degN, tot, N_NODES);
    scan_kernel<<<1, 1024, 0, stream>>>(tot, offsets, N_NODES);
    baseN_kernel<<<nb, 256, 0, stream>>>(degN, offsets, baseN, N_NODES);
    csr_write_kernel<<<eb, 256, 0, stream>>>(src, dst, pos, E, baseN, csr_src);

    int lin_grid = N_NODES / 16;   // 625, exact

    // layer 1
    aggregate_kernel<<<N_NODES, 256, 0, stream>>>(xm, offsets, csr_src, mean16);
    lin_mfma_kernel<<<lin_grid, 128, 0, stream>>>(
        mean16, xm, WT, WT + D * D, b1, m1,
        (const float*)nullptr, (const float*)nullptr, (float*)nullptr);
    // layer 2
    aggregate_kernel<<<N_NODES, 256, 0, stream>>>(m1, offsets, csr_src, mean16);
    lin_mfma_kernel<<<lin_grid, 128, 0, stream>>>(
        mean16, m1, WT + 2 * D * D, WT + 3 * D * D, b2, m2,
        (const float*)nullptr, (const float*)nullptr, (float*)nullptr);
    // layer 3 + classifier
    aggregate_kernel<<<N_NODES, 256, 0, stream>>>(m2, offsets, csr_src, mean16);
    lin_mfma_kernel<<<lin_grid, 128, 0, stream>>>(
        mean16, m2, WT + 4 * D * D, WT + 5 * D * D, b3, (__half*)nullptr,
        Wc, bc, out);
}